// Round 1
// 191.409 us; speedup vs baseline: 1.0081x; 1.0081x over previous
//
#include <hip/hip_runtime.h>
#include <hip/hip_bf16.h>
#include <stdint.h>

#define IN_F   4096
#define OUT_F  4096
#define M_ROWS 2048
#define NG     32
#define GRP    128

// ---- gemm v2 geometry: 256x128 tile, 512 thr, triple-buffered BK=128 ----
#define BM 256
#define BN 128
#define BK 128                    // one scale group per K-tile
#define NTILES (IN_F / BK)        // 32
#define ABYTES (BM * BK)          // 32768
#define BBYTES (BN * BK)          // 16384
#define BUFB   (ABYTES + BBYTES)  // 49152
#define ACHUNKS (ABYTES / 16)     // 2048

typedef int   v4i  __attribute__((ext_vector_type(4)));
typedef float f32x4 __attribute__((ext_vector_type(4)));

typedef const void __attribute__((address_space(1))) cv_g;
typedef void       __attribute__((address_space(3))) v_l;

__device__ __forceinline__ void async16(const void* g, void* l) {
  // global -> LDS DMA, 16B/lane; LDS dest = wave-uniform base + lane*16.
  __builtin_amdgcn_global_load_lds((cv_g*)g, (v_l*)l, 16, 0, 0);
}

// perm dtype flag (fallback path only): 1 if int64, 0 if int32.
__device__ int g_perm_is64;

__global__ void decode_flag(const void* __restrict__ perm_raw) {
  if (threadIdx.x == 0 && blockIdx.x == 0) {
    const int* w = (const int*)perm_raw;
    int ok = 1;
    for (int j = 0; j < 32; ++j) {
      int lo = w[2 * j], hi = w[2 * j + 1];
      if (hi != 0 || lo < 0 || lo >= IN_F) { ok = 0; break; }
    }
    g_perm_is64 = ok;
  }
}

// Fused preprocessing (int8 edition) -- unchanged from verified version.
__global__ __launch_bounds__(256) void prep(const float* __restrict__ x,
                                            const int* __restrict__ w_q,
                                            const void* __restrict__ perm_raw,
                                            char* __restrict__ xq,
                                            char* __restrict__ w8,
                                            float* __restrict__ sxr) {
  __shared__ float sx[IN_F];
  __shared__ float red[4];
  __shared__ int sflag;
  const int b = blockIdx.x;
  const int t = threadIdx.x;

  if (b < M_ROWS) {
    const int m = b;
    const float* xr = x + (size_t)m * IN_F;
#pragma unroll
    for (int u = 0; u < 4; ++u) {
      int idx = (u * 256 + t) * 4;
      *(float4*)&sx[idx] = *(const float4*)&xr[idx];
    }
    if (t < 64) {
      const int* w = (const int*)perm_raw;
      int j = t & 31;
      int lo = w[2 * j], hi = w[2 * j + 1];
      int cond = (hi == 0 && lo >= 0 && lo < IN_F);
      unsigned long long bal = __ballot(cond);
      if (t == 0) sflag = (bal == ~0ull) ? 1 : 0;
    }
    __syncthreads();
    const int f = sflag;
    const long long* p64 = (const long long*)perm_raw;
    const int*       p32 = (const int*)perm_raw;
    const int jb = t * 16;
    float vals[16];
    float lmax = 0.f;
#pragma unroll
    for (int u = 0; u < 16; ++u) {
      int pj = f ? (int)p64[jb + u] : p32[jb + u];
      float v = sx[pj];
      vals[u] = v;
      lmax = fmaxf(lmax, fabsf(v));
    }
#pragma unroll
    for (int d = 1; d < 64; d <<= 1)
      lmax = fmaxf(lmax, __shfl_xor(lmax, d, 64));
    if ((t & 63) == 0) red[t >> 6] = lmax;
    __syncthreads();
    float rmax = fmaxf(fmaxf(red[0], red[1]), fmaxf(red[2], red[3]));
    float inv = (rmax > 0.f) ? 127.f / rmax : 0.f;
    if (t == 0) sxr[m] = rmax / 127.f;
    char q[16] __attribute__((aligned(16)));
#pragma unroll
    for (int u = 0; u < 16; ++u)
      q[u] = (char)__float2int_rn(vals[u] * inv);
    *(uint4*)(xq + (size_t)m * IN_F + jb) = *(const uint4*)q;
  } else {
    const int o  = b - M_ROWS;
    const int kb = t * 16;
    const int* wr = w_q + (size_t)o * IN_F + kb;
    int4 w0 = *(const int4*)(wr + 0);
    int4 w1 = *(const int4*)(wr + 4);
    int4 w2 = *(const int4*)(wr + 8);
    int4 w3 = *(const int4*)(wr + 12);
    char q[16] __attribute__((aligned(16)));
    q[0]=(char)w0.x; q[1]=(char)w0.y; q[2]=(char)w0.z; q[3]=(char)w0.w;
    q[4]=(char)w1.x; q[5]=(char)w1.y; q[6]=(char)w1.z; q[7]=(char)w1.w;
    q[8]=(char)w2.x; q[9]=(char)w2.y; q[10]=(char)w2.z; q[11]=(char)w2.w;
    q[12]=(char)w3.x; q[13]=(char)w3.y; q[14]=(char)w3.z; q[15]=(char)w3.w;
    *(uint4*)(w8 + (size_t)o * IN_F + kb) = *(const uint4*)q;
  }
}

// C[m,o] = sxr[m] * sum_g s_w[g,o] * (int8 dot over group g) + bias[o]
//
// R9: counted-vmcnt phase pipeline (T3+T4+T5 port of the 8-phase template).
// 256x128 tile, 512 threads = 8 waves (4M x 2N) of 64x64. Triple-buffered
// LDS (3 x 48KB + 8KB s_w = 152KB, 1 block/CU): tile g+2 is staged while
// tile g computes; the target buffer was last READ in tile g-1, so
// stage-over-live-reads is impossible by construction. Raw s_barrier +
// s_waitcnt vmcnt(6) once per K-tile (12 loads/thread in flight across
// barriers; vmcnt(0) only at the last tile) -- no full drain in the main
// loop. 2 phases per tile (one per 64-wide k-slice):
//   {8x ds_read_b128 | 3x global_load_lds -> s_barrier -> setprio(1),
//    16x MFMA, setprio(0) -> s_barrier}
// Empty asm memory-clobber fences after each barrier pin DMA issues and
// ds_reads inside their region (hazard: tile g+1 stages into buf (g)%3 --
// must not hoist above the tile-entry barrier).
// Same verified 16B-chunk geometry: chunk(row,kc) at row*8 + (kc^(row&7));
// fragment reads 2-way-bank-aliased (free, SQ_LDS_BANK_CONFLICT=0).
__global__ __launch_bounds__(512, 2) void gemm_i8(
    const char* __restrict__ A,     // xq  M x K int8
    const char* __restrict__ B,     // w8  N x K int8
    const float* __restrict__ s_w,  // NG x OUT_F
    const float* __restrict__ sxr,  // M
    const float* __restrict__ bias,
    float* __restrict__ C) {
  __shared__ char smem[3][BUFB];
  __shared__ unsigned short sws[NG * BN];  // s_w for this block's 128 cols, bf16

  const int tid  = threadIdx.x;
  const int wave = tid >> 6;
  const int lane = tid & 63;
  const int bm = blockIdx.y << 8;   // 256-row tiles
  const int bn = blockIdx.x << 7;   // 128-col tiles
  const int wm = (wave >> 1) << 6;  // 4 waves along M
  const int wn = (wave & 1) << 6;   // 2 waves along N
  const int lrow = lane & 15;
  const int quad = lane >> 4;

  // stage s_w block into LDS as bf16 (K-loop stays free of global loads)
#pragma unroll
  for (int u = 0; u < 8; ++u) {
    int idx = u * 512 + tid;  // 4096 entries: [g][c]
    int g = idx >> 7, c = idx & 127;
    __hip_bfloat16 h = __float2bfloat16(s_w[(size_t)g * OUT_F + bn + c]);
    sws[idx] = *(unsigned short*)&h;
  }

  // Staging descriptors: 6 rounds/tile, each wave = 64 consecutive 16B chunks.
  // Rounds 0-3 cover A (2048 chunks), rounds 4-5 cover B (1024 chunks).
  const char* gp[6];
  int lofs[6];
#pragma unroll
  for (int h = 0; h < 6; ++h) {
    int c0 = h * 512 + wave * 64;  // wave-uniform
    int c  = c0 + lane;
    if (c0 < ACHUNKS) {
      int row = c >> 3;
      int kc  = (c & 7) ^ (row & 7);
      gp[h]   = A + (size_t)(bm + row) * IN_F + kc * 16;
      lofs[h] = c0 * 16;
    } else {
      int cb  = c - ACHUNKS;
      int row = cb >> 3;
      int kc  = (cb & 7) ^ (row & 7);
      gp[h]   = B + (size_t)(bn + row) * IN_F + kc * 16;
      lofs[h] = ABYTES + (c0 - ACHUNKS) * 16;
    }
  }

  f32x4 accf[4][4] = {};

  // prologue: stage tiles 0 and 1 (6 loads each; queue = 12)
#pragma unroll
  for (int h = 0; h < 6; ++h) async16(gp[h], &smem[0][lofs[h]]);
#pragma unroll
  for (int h = 0; h < 6; ++h) async16(gp[h] + BK, &smem[1][lofs[h]]);
  // lgkmcnt(0): drain own sws ds_writes so the barrier publishes them.
  // vmcnt(6): tile 0's 6 loads landed (tile 1's may remain in flight).
  asm volatile("s_waitcnt vmcnt(6) lgkmcnt(0)" ::: "memory");
  __builtin_amdgcn_s_barrier();
  asm volatile("" ::: "memory");

  int bufsel = 0;
  for (int g = 0; g < NTILES; ++g) {
    const char* bufA = smem[bufsel];
    const char* bufB = bufA + ABYTES;
    const int  stg   = (bufsel + 2 >= 3) ? bufsel - 1 : bufsel + 2;  // (bufsel+2)%3
    const bool do_stage = (g + 2 < NTILES);
    const int  kofs  = (g + 2) * BK;

    v4i acci[4][4] = {};
#pragma unroll
    for (int s = 0; s < 2; ++s) {
      // phase s: fragment reads (k-slice s) + half the next-next-tile staging
      v4i af[4], bf[4];
#pragma unroll
      for (int i = 0; i < 4; ++i) {
        int row = wm + i * 16 + lrow;
        af[i] = *(const v4i*)&bufA[row * BK + ((((s << 2) + quad) ^ (row & 7)) << 4)];
      }
#pragma unroll
      for (int j = 0; j < 4; ++j) {
        int row = wn + j * 16 + lrow;
        bf[j] = *(const v4i*)&bufB[row * BK + ((((s << 2) + quad) ^ (row & 7)) << 4)];
      }
      if (do_stage) {
#pragma unroll
        for (int h = s * 3; h < s * 3 + 3; ++h)
          async16(gp[h] + kofs, &smem[stg][lofs[h]]);
      }
      __builtin_amdgcn_s_barrier();
      asm volatile("" ::: "memory");
      __builtin_amdgcn_s_setprio(1);
#pragma unroll
      for (int i = 0; i < 4; ++i)
#pragma unroll
        for (int j = 0; j < 4; ++j)
          acci[i][j] = __builtin_amdgcn_mfma_i32_16x16x64_i8(af[i], bf[j], acci[i][j], 0, 0, 0);
      __builtin_amdgcn_s_setprio(0);
      if (s == 0) {
        __builtin_amdgcn_s_barrier();
        asm volatile("" ::: "memory");
      }
    }

    // per-group rescale (exact int32 -> f32, scaled by s_w[g, col]);
    // regs + read-only sws region only -- no sync needed here.
    float swv[4];
#pragma unroll
    for (int j = 0; j < 4; ++j) {
      unsigned int u = sws[g * BN + wn + j * 16 + lrow];
      swv[j] = __uint_as_float(u << 16);
    }
#pragma unroll
    for (int i = 0; i < 4; ++i)
#pragma unroll
      for (int j = 0; j < 4; ++j)
#pragma unroll
        for (int r = 0; r < 4; ++r)
          accf[i][j][r] += swv[j] * (float)acci[i][j][r];

    // tile-end sync: publish tile g+1's DMA (counted wait -- keep the
    // just-issued tile g+2 loads in flight) + guarantee all waves are done
    // reading buf (g)%3 before tile g+1 stages tile g+3 into it.
    if (g < NTILES - 1) {
      if (g < NTILES - 2) asm volatile("s_waitcnt vmcnt(6)" ::: "memory");
      else                asm volatile("s_waitcnt vmcnt(0)" ::: "memory");
      __builtin_amdgcn_s_barrier();
      asm volatile("" ::: "memory");
    }
    bufsel = (bufsel + 1 == 3) ? 0 : bufsel + 1;
  }

  // Epilogue: C/D layout col=lane&15, row=quad*4+reg (dtype-independent).
#pragma unroll
  for (int i = 0; i < 4; ++i) {
    int r0 = bm + wm + i * 16 + quad * 4;
    float sxv[4];
#pragma unroll
    for (int r = 0; r < 4; ++r) sxv[r] = sxr[r0 + r];
#pragma unroll
    for (int j = 0; j < 4; ++j) {
      int col = bn + wn + j * 16 + lrow;
      float bv = bias[col];
#pragma unroll
      for (int r = 0; r < 4; ++r)
        C[(size_t)(r0 + r) * OUT_F + col] = sxv[r] * accf[i][j][r] + bv;
    }
  }
}

// Correct-but-slow fp32 fallback if workspace is too small.
__global__ void naive_fallback(const float* __restrict__ x, const int* __restrict__ w_q,
                               const float* __restrict__ s_w, const void* __restrict__ perm_raw,
                               const float* __restrict__ bias, float* __restrict__ out) {
  int t = blockIdx.x * blockDim.x + threadIdx.x;
  int m = t >> 12;
  int o = t & 4095;
  const int f = g_perm_is64;
  const long long* p64 = (const long long*)perm_raw;
  const int*       p32 = (const int*)perm_raw;
  const float* xr = x + (size_t)m * IN_F;
  const int*   wr = w_q + (size_t)o * IN_F;
  float acc = 0.f;
  for (int g = 0; g < NG; ++g) {
    float part = 0.f;
    for (int k = 0; k < GRP; ++k) {
      int j = g * GRP + k;
      int pj = f ? (int)p64[j] : p32[j];
      part += xr[pj] * (float)wr[j];
    }
    acc += part * s_w[(size_t)g * OUT_F + o];
  }
  out[t] = acc + bias[o];
}

extern "C" void kernel_launch(void* const* d_in, const int* in_sizes, int n_in,
                              void* d_out, int out_size, void* d_ws, size_t ws_size,
                              hipStream_t stream) {
  const float* x    = (const float*)d_in[0];
  const int*   w_q  = (const int*)d_in[1];
  const float* s_w  = (const float*)d_in[2];
  const void*  perm = d_in[3];   // int64 or int32 -- detected on device
  const float* bias = (const float*)d_in[4];
  float* out = (float*)d_out;

  const size_t xq_bytes = (size_t)M_ROWS * IN_F;            // 8 MiB int8
  const size_t w8_bytes = (size_t)OUT_F * IN_F;             // 16 MiB int8
  const size_t sx_bytes = (size_t)M_ROWS * sizeof(float);   // 8 KiB
  const size_t need = xq_bytes + w8_bytes + sx_bytes;

  if (ws_size < need) {
    decode_flag<<<1, 64, 0, stream>>>(perm);
    naive_fallback<<<(M_ROWS * OUT_F) / 256, 256, 0, stream>>>(x, w_q, s_w, perm, bias, out);
    return;
  }

  char*  xq  = (char*)d_ws;
  char*  w8  = (char*)d_ws + xq_bytes;
  float* sxr = (float*)((char*)d_ws + xq_bytes + w8_bytes);

  prep<<<M_ROWS + OUT_F, 256, 0, stream>>>(x, w_q, perm, xq, w8, sxr);

  dim3 grid(OUT_F / BN, M_ROWS / BM);  // 32 x 8 = 256 blocks, 1/CU
  gemm_i8<<<grid, 512, 0, stream>>>(xq, w8, s_w, sxr, bias, out);
}